// Round 9
// baseline (284.262 us; speedup 1.0000x reference)
//
#include <hip/hip_runtime.h>
#include <hip/hip_bf16.h>

// ---------------------------------------------------------------------------
// SelfAttention: y = proj(attn(qkv(x)))   B=4 T=2048 C=1024 H=16 HD=64
// Round 9 = round 8 resubmitted verbatim (bench infra failed; kernel audit
// found no deadlock/hang vector: uniform barriers, sound 2-barrier dbuf).
// Round 8: async double-buffered K/V staging in attn (T14).
//  - K/V[2] LDS buffers (36.9KB); loop top writes prefetched regs -> buf[kt&1]
//  - next tile's global loads (+pad) issued right after barrier A; latency
//    hides under QK^T + softmax (~400+ cyc)
//  - 2 barriers/tile, no end-of-tile barrier (safe: any wave at tile kt+1's
//    stage-write passed barriers A(kt)+B(kt); barrier A(kt) is not passable
//    until all waves finished tile kt-1's reads of that same buffer)
//  - VGPR 80->~96 stays in the 65-128 band: prefetch is occupancy-free now
//  Keeps: rotation-swizzled P (round 7), swapped QK^T in-register softmax,
//  transposed-V, ballot mask, supertile GEMM remap.
// ---------------------------------------------------------------------------

using short8  = __attribute__((ext_vector_type(8))) short;
using short4_ = __attribute__((ext_vector_type(4))) short;
using float4_ = __attribute__((ext_vector_type(4))) float;

#define Bb   4
#define Tt   2048
#define Cc   1024
#define Hh   16
#define HDd  64

__device__ __forceinline__ float bf2f(unsigned short u) {
    union { float f; unsigned int i; } x; x.i = ((unsigned int)u) << 16; return x.f;
}
__device__ __forceinline__ unsigned short f2bf(float f) {
    union { float f; unsigned int i; } x; x.f = f;
    unsigned int r = x.i + 0x7fff + ((x.i >> 16) & 1);
    return (unsigned short)(r >> 16);
}
__device__ __forceinline__ float4_ bmfma(short8 a, short8 b, float4_ c) {
    return __builtin_amdgcn_mfma_f32_16x16x32_bf16(a, b, c, 0, 0, 0);
}
// 2^x — compiler-emitted v_exp_f32 (hazard-safe)
__device__ __forceinline__ float ex2(float x) {
    return __builtin_amdgcn_exp2f(x);
}
__device__ __forceinline__ void gl2lds16(const unsigned short* g, unsigned short* l) {
    __builtin_amdgcn_global_load_lds(
        (const __attribute__((address_space(1))) void*)g,
        (__attribute__((address_space(3))) void*)l, 16, 0, 0);
}

// ---------------------------------------------------------------------------
// x f32 -> bf16 (flat)
// ---------------------------------------------------------------------------
__global__ __launch_bounds__(256) void convert_f32_bf16(
    const float* __restrict__ in, unsigned short* __restrict__ out)
{
    size_t idx = ((size_t)blockIdx.x * 256 + threadIdx.x) * 8;
    float4_ f0 = *(const float4_*)&in[idx];
    float4_ f1 = *(const float4_*)&in[idx + 4];
    short8 h;
    h[0] = (short)f2bf(f0[0]); h[1] = (short)f2bf(f0[1]);
    h[2] = (short)f2bf(f0[2]); h[3] = (short)f2bf(f0[3]);
    h[4] = (short)f2bf(f1[0]); h[5] = (short)f2bf(f1[1]);
    h[6] = (short)f2bf(f1[2]); h[7] = (short)f2bf(f1[3]);
    *(short8*)&out[idx] = h;
}

// ---------------------------------------------------------------------------
// Transpose + convert: in f32 [R][Ccols] -> out bf16 [Ccols][R]
// ---------------------------------------------------------------------------
__global__ __launch_bounds__(256) void transpose_f32_bf16(
    const float* __restrict__ in, unsigned short* __restrict__ out,
    int R, int Ccols)
{
    __shared__ unsigned short tile[32][33];
    int c0 = blockIdx.x * 32, r0 = blockIdx.y * 32;
    int tx = threadIdx.x & 31, ty = threadIdx.x >> 5;   // ty 0..7
    for (int o = 0; o < 32; o += 8)
        tile[ty + o][tx] = f2bf(in[(size_t)(r0 + ty + o) * Ccols + c0 + tx]);
    __syncthreads();
    for (int o = 0; o < 32; o += 8)
        out[(size_t)(c0 + ty + o) * R + r0 + tx] = tile[tx][ty + o];
}

// ---------------------------------------------------------------------------
// m97-style GEMM main loop: C = A[M][K](bf16) * Bt[N][K](bf16)^T
// 128x128 block tile, BK=64, 4 waves each computing 64x64 via 4x4 MFMA.
// swapT: compute C^T fragments (mfma(b,a)) — acc[i][j]: i = n-tile, j = m-tile.
// ---------------------------------------------------------------------------
#define GBK 64

__device__ __forceinline__ void gemm128_main(
    const unsigned short* __restrict__ A, const unsigned short* __restrict__ Bt,
    int K, int m0, int n0,
    unsigned short* As, unsigned short* Bs, float4_ acc[4][4], bool swapT)
{
    int tid  = threadIdx.x;
    int wave = tid >> 6, lane = tid & 63;
    int wm = (wave >> 1) * 64, wn = (wave & 1) * 64;
    int lr = lane & 15, lg = lane >> 4;
    int srow = tid >> 3;            // 0..31
    int scol = (tid & 7) * 8;       // 0..56

    for (int k0 = 0; k0 < K; k0 += GBK) {
        #pragma unroll
        for (int j = 0; j < 4; j++) {
            int row = j * 32 + srow;
            gl2lds16(&A [(size_t)(m0 + row) * K + k0 + scol], &As[row * GBK + scol]);
            gl2lds16(&Bt[(size_t)(n0 + row) * K + k0 + scol], &Bs[row * GBK + scol]);
        }
        __syncthreads();
        #pragma unroll
        for (int ks = 0; ks < GBK; ks += 32) {
            short8 af[4], bf[4];
            #pragma unroll
            for (int i = 0; i < 4; i++) {
                af[i] = *(const short8*)&As[(wm + i * 16 + lr) * GBK + ks + lg * 8];
                bf[i] = *(const short8*)&Bs[(wn + i * 16 + lr) * GBK + ks + lg * 8];
            }
            if (!swapT) {
                #pragma unroll
                for (int i = 0; i < 4; i++)
                    #pragma unroll
                    for (int j = 0; j < 4; j++)
                        acc[i][j] = bmfma(af[i], bf[j], acc[i][j]);
            } else {
                #pragma unroll
                for (int i = 0; i < 4; i++)
                    #pragma unroll
                    for (int j = 0; j < 4; j++)
                        acc[i][j] = bmfma(bf[i], af[j], acc[i][j]);
            }
        }
        __syncthreads();
    }
}

// 8x8 supertile remap (requires gridDim.x == 64). Bijective:
// mt from (by&7, bx&7), nt from (by>>3, bx>>3). 64 consecutive blocks =
// one 8x8 supertile -> A+B working set ~4MB (L2-resident per XCD).
__device__ __forceinline__ void supertile_remap(int& m0, int& n0)
{
    int bx = blockIdx.x, by = blockIdx.y;
    int mt = ((by & 7) << 3) | (bx & 7);
    int nt = ((by >> 3) << 3) | (bx >> 3);
    m0 = mt * 128; n0 = nt * 128;
}

__global__ __launch_bounds__(256) void gemm_qkv(
    const unsigned short* __restrict__ A,   // x: [8192][1024] bf16
    const unsigned short* __restrict__ Bt,  // w_attn^T: [3072][1024] bf16
    unsigned short* __restrict__ Q,         // [B][H][T][HD] bf16 (pre-scaled 0.125*log2e)
    unsigned short* __restrict__ Ko,        // [B][H][T][HD] bf16
    unsigned short* __restrict__ V)         // [B][H][HD][T] bf16 (TRANSPOSED)
{
    __shared__ unsigned short As[128 * GBK];
    __shared__ unsigned short Bs[128 * GBK];
    int m0, n0;
    supertile_remap(m0, n0);
    bool vblk = (n0 >= 2048);               // V-region tile -> compute C^T
    float4_ acc[4][4] = {};
    gemm128_main(A, Bt, 1024, m0, n0, As, Bs, acc, vblk);

    int lane = threadIdx.x & 63, wave = threadIdx.x >> 6;
    int wm = (wave >> 1) * 64, wn = (wave & 1) * 64;
    int lr = lane & 15, lg = lane >> 4;
    if (!vblk) {
        // Q/K: normal orientation. Fold (1/sqrt(64))*log2(e) into Q for exp2.
        #pragma unroll
        for (int i = 0; i < 4; i++)
            #pragma unroll
            for (int j = 0; j < 4; j++) {
                int n = n0 + wn + 16 * j + lr;
                int which = n >> 10;
                int c = n & 1023;
                int h = c >> 6, d = c & 63;
                unsigned short* dst = (which == 0) ? Q : Ko;
                float sc2 = (which == 0) ? 0.1803368801f : 1.0f;  // 0.125*log2e
                #pragma unroll
                for (int r = 0; r < 4; r++) {
                    int m = m0 + wm + 16 * i + lg * 4 + r;
                    int b = m >> 11, t = m & 2047;
                    dst[(((size_t)(b * Hh + h) * Tt) + t) * HDd + d] = f2bf(acc[i][j][r] * sc2);
                }
            }
    } else {
        // V: acc holds C^T — lane&15 = m (t, contiguous), (lg,reg) = n (d).
        #pragma unroll
        for (int i = 0; i < 4; i++)          // n-tile
            #pragma unroll
            for (int j = 0; j < 4; j++) {    // m-tile
                int m = m0 + wm + 16 * j + lr;
                int b = m >> 11, t = m & 2047;
                #pragma unroll
                for (int r = 0; r < 4; r++) {
                    int n = n0 + wn + 16 * i + lg * 4 + r;
                    int c = n - 2048;
                    int h = c >> 6, d = c & 63;
                    V[(((size_t)(b * Hh + h) * HDd) + d) * Tt + t] = f2bf(acc[i][j][r]);
                }
            }
    }
}

__global__ __launch_bounds__(256) void gemm_proj(
    const unsigned short* __restrict__ A,   // y: [8192][1024] bf16
    const unsigned short* __restrict__ Bt,  // w_proj^T: [1024][1024] bf16
    const float* __restrict__ bias,         // [1024] f32
    float* __restrict__ Out)                // [8192][1024] f32
{
    __shared__ unsigned short As[128 * GBK];
    __shared__ unsigned short Bs[128 * GBK];
    int m0, n0;
    supertile_remap(m0, n0);
    float4_ acc[4][4] = {};
    gemm128_main(A, Bt, 1024, m0, n0, As, Bs, acc, false);

    int lane = threadIdx.x & 63, wave = threadIdx.x >> 6;
    int wm = (wave >> 1) * 64, wn = (wave & 1) * 64;
    int lr = lane & 15, lg = lane >> 4;
    #pragma unroll
    for (int i = 0; i < 4; i++)
        #pragma unroll
        for (int j = 0; j < 4; j++) {
            int n = n0 + wn + 16 * j + lr;
            float bv = bias[n];
            #pragma unroll
            for (int r = 0; r < 4; r++) {
                int m = m0 + wm + 16 * i + lg * 4 + r;
                Out[(size_t)m * 1024 + n] = acc[i][j][r] + bv;
            }
        }
}

// ---------------------------------------------------------------------------
// Flash attention (causal + key pad mask), swapped-QK^T (S^T) softmax,
// double-buffered async K/V staging.
// K staged [key][d], V staged [d][key] (global V pre-transposed).
// Row stride DPAD=72 elems (144B). P-tile rotation swizzle (round 7).
// ---------------------------------------------------------------------------
#define DPAD 72   // padded row stride (elems) = 144B

__global__ __launch_bounds__(256) void attn_fwd(
    const unsigned short* __restrict__ Q,   // [B][H][T][HD], pre-scaled 0.125*log2e
    const unsigned short* __restrict__ Kg,  // [B][H][T][HD]
    const unsigned short* __restrict__ Vg,  // [B][H][HD][T]  (transposed)
    const int* __restrict__ pad,            // [B][T]
    unsigned short* __restrict__ Y)         // [B][T][C]
{
    // [buf][K=0/V=1][64][DPAD] : 2 x 2 x 64 x 72 shorts = 36864 B
    __shared__ unsigned short smem[4 * 64 * DPAD];

    int flat = blockIdx.x;          // 0..2047
    int qb = 31 - (flat >> 6);      // heavy-first (LPT)
    int bh = flat & 63;
    int b  = bh >> 4, h = bh & 15;
    const size_t base = (size_t)bh * Tt * HDd;
    int tid  = threadIdx.x;
    int wave = tid >> 6, lane = tid & 63;
    int lr = lane & 15, lg = lane >> 4;
    int q0 = qb * 64 + wave * 16;
    const int* padRow = pad + b * Tt;

    int r8 = tid >> 3;              // staging row 0..31 (and +32)
    int c8 = (tid & 7) * 8;         // staging col {0,8,...,56}

    short8 qf0 = *(const short8*)&Q[base + (size_t)(q0 + lr) * HDd + lg * 8];
    short8 qf1 = *(const short8*)&Q[base + (size_t)(q0 + lr) * HDd + 32 + lg * 8];

    // per-lane scalars: this lane's q-row is q0 + lr (replicated over lg)
    float m_i = -1e30f, l_i = 0.f;
    float4_ o_acc[4];
    #pragma unroll
    for (int dt = 0; dt < 4; dt++) o_acc[dt] = (float4_){0.f, 0.f, 0.f, 0.f};

    // P rotation-swizzle constants
    int ebase = (lg & 1) * 4;        // k&7 base of this lane's 4 keys
    int hnib  = lg >> 1;             // kb low bit source
    int q2    = (2 * lr) & 7;        // 2q mod 8

    // ---- prologue: prefetch tile 0 into registers ----
    short8 kr0 = *(const short8*)&Kg[base + (size_t)r8 * HDd + c8];
    short8 kr1 = *(const short8*)&Kg[base + (size_t)(r8 + 32) * HDd + c8];
    short8 vr0 = *(const short8*)&Vg[base + (size_t)r8 * Tt + c8];
    short8 vr1 = *(const short8*)&Vg[base + (size_t)(r8 + 32) * Tt + c8];
    int pvld = padRow[lane];

    for (int kt = 0; kt <= qb; kt++) {
        int cur = kt & 1;
        unsigned short* Kt = smem + cur * (2 * 64 * DPAD);   // [key][d]
        unsigned short* Vt = Kt + 64 * DPAD;                 // [d][key]
        // ---- write prefetched regs -> LDS (conflict-free full-row map) ----
        *(short8*)&Kt[r8 * DPAD + c8]        = kr0;
        *(short8*)&Kt[(r8 + 32) * DPAD + c8] = kr1;
        *(short8*)&Vt[r8 * DPAD + c8]        = vr0;
        *(short8*)&Vt[(r8 + 32) * DPAD + c8] = vr1;
        unsigned long long pm = __ballot(pvld != 0);
        __syncthreads();                                     // barrier A

        // ---- issue next tile's loads; land during QK + softmax ----
        if (kt < qb) {
            int k1 = kt * 64 + 64;
            kr0 = *(const short8*)&Kg[base + (size_t)(k1 + r8) * HDd + c8];
            kr1 = *(const short8*)&Kg[base + (size_t)(k1 + r8 + 32) * HDd + c8];
            vr0 = *(const short8*)&Vg[base + (size_t)r8 * Tt + k1 + c8];
            vr1 = *(const short8*)&Vg[base + (size_t)(r8 + 32) * Tt + k1 + c8];
            pvld = padRow[k1 + lane];
        }

        // ---- S^T = (K Q^T): rows = keys, cols = q  (swapped operands) ----
        float4_ s[4];
        #pragma unroll
        for (int nt = 0; nt < 4; nt++) {
            short8 kf0 = *(const short8*)&Kt[(nt * 16 + lr) * DPAD + lg * 8];
            short8 kf1 = *(const short8*)&Kt[(nt * 16 + lr) * DPAD + 32 + lg * 8];
            float4_ a = (float4_){0.f, 0.f, 0.f, 0.f};
            a = bmfma(kf0, qf0, a);
            a = bmfma(kf1, qf1, a);
            s[nt] = a;   // s[nt][r]: key = nt*16 + lg*4 + r, q = lr
        }
        // ---- masking (S^T indices) ----
        if (kt == qb) {
            #pragma unroll
            for (int nt = 0; nt < 4; nt++)
                #pragma unroll
                for (int r = 0; r < 4; r++) {
                    int kl = nt * 16 + lg * 4 + r;       // key local
                    bool kpv = (pm >> kl) & 1ull;
                    // causal: key k0+kl vs qrow q0+lr  ->  kl vs wave*16+lr
                    if (!kpv || kl > wave * 16 + lr) s[nt][r] = -1e30f;
                }
        } else if (pm != ~0ull) {
            #pragma unroll
            for (int nt = 0; nt < 4; nt++)
                #pragma unroll
                for (int r = 0; r < 4; r++) {
                    int kl = nt * 16 + lg * 4 + r;
                    bool kpv = (pm >> kl) & 1ull;
                    s[nt][r] = kpv ? s[nt][r] : -1e30f;
                }
        }
        // ---- online softmax (base 2), per-lane scalar state ----
        float v = fmaxf(fmaxf(s[0][0], s[0][1]), fmaxf(s[0][2], s[0][3]));
        #pragma unroll
        for (int nt = 1; nt < 4; nt++)
            v = fmaxf(v, fmaxf(fmaxf(s[nt][0], s[nt][1]), fmaxf(s[nt][2], s[nt][3])));
        v = fmaxf(v, __shfl_xor(v, 16, 64));
        v = fmaxf(v, __shfl_xor(v, 32, 64));
        float m_new = fmaxf(m_i, v);
        float alpha = ex2(m_i - m_new);
        float rsum = 0.f;
        #pragma unroll
        for (int nt = 0; nt < 4; nt++)
            #pragma unroll
            for (int r = 0; r < 4; r++) {
                float p = ex2(s[nt][r] - m_new);
                s[nt][r] = p;
                rsum += p;
            }
        rsum += __shfl_xor(rsum, 16, 64);
        rsum += __shfl_xor(rsum, 32, 64);
        l_i = l_i * alpha + rsum;
        m_i = m_new;

        // ---- broadcast alpha to o_acc layout (q = lg*4+r) and rescale ----
        #pragma unroll
        for (int r = 0; r < 4; r++) {
            float ar = __shfl(alpha, (lg << 2) + r, 64);
            #pragma unroll
            for (int dt = 0; dt < 4; dt++)
                o_acc[dt][r] *= ar;
        }

        __syncthreads();   // barrier B: all waves done reading Kt -> P alias ok

        // ---- P: 4x packed b64 writes, rotation swizzle p=(kb-2q)&7 ----
        unsigned short* Pw = &Kt[wave * 16 * DPAD];   // per-wave slice (Kt alias)
        #pragma unroll
        for (int nt = 0; nt < 4; nt++) {
            short4_ w;
            w[0] = (short)f2bf(s[nt][0]); w[1] = (short)f2bf(s[nt][1]);
            w[2] = (short)f2bf(s[nt][2]); w[3] = (short)f2bf(s[nt][3]);
            int p = (2 * nt + hnib - q2) & 7;
            *(short4_*)&Pw[lr * DPAD + p * 8 + ebase] = w;
        }
        // ---- O += P @ V  (pf reads: p=(kb-2q)&7, kb=lg / 4+lg) ----
        short8 pf0 = *(const short8*)&Pw[lr * DPAD + (((lg - q2) & 7) << 3)];
        short8 pf1 = *(const short8*)&Pw[lr * DPAD + (((4 + lg - q2) & 7) << 3)];
        #pragma unroll
        for (int dt = 0; dt < 4; dt++) {
            int d = dt * 16 + lr;
            short8 vf0 = *(const short8*)&Vt[d * DPAD + lg * 8];
            short8 vf1 = *(const short8*)&Vt[d * DPAD + 32 + lg * 8];
            o_acc[dt] = bmfma(pf0, vf0, o_acc[dt]);
            o_acc[dt] = bmfma(pf1, vf1, o_acc[dt]);
        }
        // no end-of-tile barrier: next tile stages into the other buffer;
        // cross-wave reuse of THIS buffer is fenced by the next barrier A+B.
    }

    // ---- epilogue: Y[b][t][h*64+d] = O / l  (l broadcast to q=lg*4+r) ----
    #pragma unroll
    for (int r = 0; r < 4; r++) {
        float lr_ = __shfl(l_i, (lg << 2) + r, 64);
        int qrow = q0 + lg * 4 + r;
        #pragma unroll
        for (int dt = 0; dt < 4; dt++)
            Y[((size_t)b * Tt + qrow) * Cc + h * HDd + dt * 16 + lr] =
                f2bf(o_acc[dt][r] / lr_);
    }
}

// ---------------------------------------------------------------------------
extern "C" void kernel_launch(void* const* d_in, const int* in_sizes, int n_in,
                              void* d_out, int out_size, void* d_ws, size_t ws_size,
                              hipStream_t stream)
{
    const float* x      = (const float*)d_in[0];
    const int*   pad    = (const int*)d_in[1];
    const float* w_attn = (const float*)d_in[2];
    const float* w_proj = (const float*)d_in[3];
    const float* b_proj = (const float*)d_in[4];
    float*       out    = (float*)d_out;

    // workspace carve-up (bf16 elems). Yb aliases Xb (x-bf16 dead after qkv).
    unsigned short* Wta = (unsigned short*)d_ws;            // 3072*1024
    unsigned short* Wtp = Wta + (size_t)3072 * 1024;        // 1024*1024
    unsigned short* Xb  = Wtp + (size_t)1024 * 1024;        // 8192*1024
    unsigned short* Yb  = Xb;                               // alias
    unsigned short* Qb  = Xb + (size_t)8192 * 1024;
    unsigned short* Kb  = Qb + (size_t)Bb * Hh * Tt * HDd;
    unsigned short* Vb  = Kb + (size_t)Bb * Hh * Tt * HDd;  // [B][H][HD][T]

    // 0) x f32 -> bf16
    convert_f32_bf16<<<dim3(4096), 256, 0, stream>>>(x, Xb);
    // 1) transpose+convert weights to bf16 [N][K]
    transpose_f32_bf16<<<dim3(3072 / 32, 1024 / 32), 256, 0, stream>>>(w_attn, Wta, 1024, 3072);
    transpose_f32_bf16<<<dim3(1024 / 32, 1024 / 32), 256, 0, stream>>>(w_proj, Wtp, 1024, 1024);
    // 2) qkv = x @ w_attn -> head-major Q/K (bf16, Q pre-scaled) + transposed V
    gemm_qkv<<<dim3(8192 / 128, 3072 / 128), 256, 0, stream>>>(Xb, Wta, Qb, Kb, Vb);
    // 3) flash attention (flat grid, heavy-first)
    attn_fwd<<<dim3(2048), 256, 0, stream>>>(Qb, Kb, Vb, pad, Yb);
    // 4) out = y @ w_proj + b_proj (f32 out)
    gemm_proj<<<dim3(8192 / 128, 1024 / 128), 256, 0, stream>>>(Yb, Wtp, b_proj, out);
}

// Round 10
// 275.931 us; speedup vs baseline: 1.0302x; 1.0302x over previous
//
#include <hip/hip_runtime.h>
#include <hip/hip_bf16.h>

// ---------------------------------------------------------------------------
// SelfAttention: y = proj(attn(qkv(x)))   B=4 T=2048 C=1024 H=16 HD=64
// Round 10: attack the VALU pipe (59% busy vs 14.6% MFMA, 4:1 = measured
// instruction-mix ratio). Two changes in attn_fwd only:
//  (1) T12: P-tile f32->bf16 via 8x inline-asm v_cvt_pk_bf16_f32 (plain VALU
//      VOP3, no trans-op hazard) replacing 16 manual-RNE f2bf (~90 VALU
//      instrs -> 8). Same RNE rounding, same byte layout.
//  (2) T13: defer-max (THR=8 base-2): skip alpha exp2 + 4-shuffle broadcast +
//      16-mul o_acc rescale when __any(v > m_i + 8) is false (wave-uniform).
//      P bounded by 2^8; exact math otherwise.
// Keeps: round-9 dbuf staging, rotation-swizzled P, swapped QK^T softmax,
// transposed-V, ballot mask, supertile GEMM remap.
// ---------------------------------------------------------------------------

using short8  = __attribute__((ext_vector_type(8))) short;
using short4_ = __attribute__((ext_vector_type(4))) short;
using uint2_  = __attribute__((ext_vector_type(2))) unsigned int;
using float4_ = __attribute__((ext_vector_type(4))) float;

#define Bb   4
#define Tt   2048
#define Cc   1024
#define Hh   16
#define HDd  64

__device__ __forceinline__ float bf2f(unsigned short u) {
    union { float f; unsigned int i; } x; x.i = ((unsigned int)u) << 16; return x.f;
}
__device__ __forceinline__ unsigned short f2bf(float f) {
    union { float f; unsigned int i; } x; x.f = f;
    unsigned int r = x.i + 0x7fff + ((x.i >> 16) & 1);
    return (unsigned short)(r >> 16);
}
// packed f32x2 -> bf16x2 (RNE), single VALU instruction
__device__ __forceinline__ unsigned int cvtpk_bf16(float lo, float hi) {
    unsigned int r;
    asm("v_cvt_pk_bf16_f32 %0, %1, %2" : "=v"(r) : "v"(lo), "v"(hi));
    return r;
}
__device__ __forceinline__ float4_ bmfma(short8 a, short8 b, float4_ c) {
    return __builtin_amdgcn_mfma_f32_16x16x32_bf16(a, b, c, 0, 0, 0);
}
// 2^x — compiler-emitted v_exp_f32 (hazard-safe)
__device__ __forceinline__ float ex2(float x) {
    return __builtin_amdgcn_exp2f(x);
}
__device__ __forceinline__ void gl2lds16(const unsigned short* g, unsigned short* l) {
    __builtin_amdgcn_global_load_lds(
        (const __attribute__((address_space(1))) void*)g,
        (__attribute__((address_space(3))) void*)l, 16, 0, 0);
}

// ---------------------------------------------------------------------------
// x f32 -> bf16 (flat)
// ---------------------------------------------------------------------------
__global__ __launch_bounds__(256) void convert_f32_bf16(
    const float* __restrict__ in, unsigned short* __restrict__ out)
{
    size_t idx = ((size_t)blockIdx.x * 256 + threadIdx.x) * 8;
    float4_ f0 = *(const float4_*)&in[idx];
    float4_ f1 = *(const float4_*)&in[idx + 4];
    short8 h;
    h[0] = (short)f2bf(f0[0]); h[1] = (short)f2bf(f0[1]);
    h[2] = (short)f2bf(f0[2]); h[3] = (short)f2bf(f0[3]);
    h[4] = (short)f2bf(f1[0]); h[5] = (short)f2bf(f1[1]);
    h[6] = (short)f2bf(f1[2]); h[7] = (short)f2bf(f1[3]);
    *(short8*)&out[idx] = h;
}

// ---------------------------------------------------------------------------
// Transpose + convert: in f32 [R][Ccols] -> out bf16 [Ccols][R]
// ---------------------------------------------------------------------------
__global__ __launch_bounds__(256) void transpose_f32_bf16(
    const float* __restrict__ in, unsigned short* __restrict__ out,
    int R, int Ccols)
{
    __shared__ unsigned short tile[32][33];
    int c0 = blockIdx.x * 32, r0 = blockIdx.y * 32;
    int tx = threadIdx.x & 31, ty = threadIdx.x >> 5;   // ty 0..7
    for (int o = 0; o < 32; o += 8)
        tile[ty + o][tx] = f2bf(in[(size_t)(r0 + ty + o) * Ccols + c0 + tx]);
    __syncthreads();
    for (int o = 0; o < 32; o += 8)
        out[(size_t)(c0 + ty + o) * R + r0 + tx] = tile[tx][ty + o];
}

// ---------------------------------------------------------------------------
// m97-style GEMM main loop: C = A[M][K](bf16) * Bt[N][K](bf16)^T
// 128x128 block tile, BK=64, 4 waves each computing 64x64 via 4x4 MFMA.
// swapT: compute C^T fragments (mfma(b,a)) — acc[i][j]: i = n-tile, j = m-tile.
// ---------------------------------------------------------------------------
#define GBK 64

__device__ __forceinline__ void gemm128_main(
    const unsigned short* __restrict__ A, const unsigned short* __restrict__ Bt,
    int K, int m0, int n0,
    unsigned short* As, unsigned short* Bs, float4_ acc[4][4], bool swapT)
{
    int tid  = threadIdx.x;
    int wave = tid >> 6, lane = tid & 63;
    int wm = (wave >> 1) * 64, wn = (wave & 1) * 64;
    int lr = lane & 15, lg = lane >> 4;
    int srow = tid >> 3;            // 0..31
    int scol = (tid & 7) * 8;       // 0..56

    for (int k0 = 0; k0 < K; k0 += GBK) {
        #pragma unroll
        for (int j = 0; j < 4; j++) {
            int row = j * 32 + srow;
            gl2lds16(&A [(size_t)(m0 + row) * K + k0 + scol], &As[row * GBK + scol]);
            gl2lds16(&Bt[(size_t)(n0 + row) * K + k0 + scol], &Bs[row * GBK + scol]);
        }
        __syncthreads();
        #pragma unroll
        for (int ks = 0; ks < GBK; ks += 32) {
            short8 af[4], bf[4];
            #pragma unroll
            for (int i = 0; i < 4; i++) {
                af[i] = *(const short8*)&As[(wm + i * 16 + lr) * GBK + ks + lg * 8];
                bf[i] = *(const short8*)&Bs[(wn + i * 16 + lr) * GBK + ks + lg * 8];
            }
            if (!swapT) {
                #pragma unroll
                for (int i = 0; i < 4; i++)
                    #pragma unroll
                    for (int j = 0; j < 4; j++)
                        acc[i][j] = bmfma(af[i], bf[j], acc[i][j]);
            } else {
                #pragma unroll
                for (int i = 0; i < 4; i++)
                    #pragma unroll
                    for (int j = 0; j < 4; j++)
                        acc[i][j] = bmfma(bf[i], af[j], acc[i][j]);
            }
        }
        __syncthreads();
    }
}

// 8x8 supertile remap (requires gridDim.x == 64). Bijective:
// mt from (by&7, bx&7), nt from (by>>3, bx>>3). 64 consecutive blocks =
// one 8x8 supertile -> A+B working set ~4MB (L2-resident per XCD).
__device__ __forceinline__ void supertile_remap(int& m0, int& n0)
{
    int bx = blockIdx.x, by = blockIdx.y;
    int mt = ((by & 7) << 3) | (bx & 7);
    int nt = ((by >> 3) << 3) | (bx >> 3);
    m0 = mt * 128; n0 = nt * 128;
}

__global__ __launch_bounds__(256) void gemm_qkv(
    const unsigned short* __restrict__ A,   // x: [8192][1024] bf16
    const unsigned short* __restrict__ Bt,  // w_attn^T: [3072][1024] bf16
    unsigned short* __restrict__ Q,         // [B][H][T][HD] bf16 (pre-scaled 0.125*log2e)
    unsigned short* __restrict__ Ko,        // [B][H][T][HD] bf16
    unsigned short* __restrict__ V)         // [B][H][HD][T] bf16 (TRANSPOSED)
{
    __shared__ unsigned short As[128 * GBK];
    __shared__ unsigned short Bs[128 * GBK];
    int m0, n0;
    supertile_remap(m0, n0);
    bool vblk = (n0 >= 2048);               // V-region tile -> compute C^T
    float4_ acc[4][4] = {};
    gemm128_main(A, Bt, 1024, m0, n0, As, Bs, acc, vblk);

    int lane = threadIdx.x & 63, wave = threadIdx.x >> 6;
    int wm = (wave >> 1) * 64, wn = (wave & 1) * 64;
    int lr = lane & 15, lg = lane >> 4;
    if (!vblk) {
        // Q/K: normal orientation. Fold (1/sqrt(64))*log2(e) into Q for exp2.
        #pragma unroll
        for (int i = 0; i < 4; i++)
            #pragma unroll
            for (int j = 0; j < 4; j++) {
                int n = n0 + wn + 16 * j + lr;
                int which = n >> 10;
                int c = n & 1023;
                int h = c >> 6, d = c & 63;
                unsigned short* dst = (which == 0) ? Q : Ko;
                float sc2 = (which == 0) ? 0.1803368801f : 1.0f;  // 0.125*log2e
                #pragma unroll
                for (int r = 0; r < 4; r++) {
                    int m = m0 + wm + 16 * i + lg * 4 + r;
                    int b = m >> 11, t = m & 2047;
                    dst[(((size_t)(b * Hh + h) * Tt) + t) * HDd + d] = f2bf(acc[i][j][r] * sc2);
                }
            }
    } else {
        // V: acc holds C^T — lane&15 = m (t, contiguous), (lg,reg) = n (d).
        #pragma unroll
        for (int i = 0; i < 4; i++)          // n-tile
            #pragma unroll
            for (int j = 0; j < 4; j++) {    // m-tile
                int m = m0 + wm + 16 * j + lr;
                int b = m >> 11, t = m & 2047;
                #pragma unroll
                for (int r = 0; r < 4; r++) {
                    int n = n0 + wn + 16 * i + lg * 4 + r;
                    int c = n - 2048;
                    int h = c >> 6, d = c & 63;
                    V[(((size_t)(b * Hh + h) * HDd) + d) * Tt + t] = f2bf(acc[i][j][r]);
                }
            }
    }
}

__global__ __launch_bounds__(256) void gemm_proj(
    const unsigned short* __restrict__ A,   // y: [8192][1024] bf16
    const unsigned short* __restrict__ Bt,  // w_proj^T: [1024][1024] bf16
    const float* __restrict__ bias,         // [1024] f32
    float* __restrict__ Out)                // [8192][1024] f32
{
    __shared__ unsigned short As[128 * GBK];
    __shared__ unsigned short Bs[128 * GBK];
    int m0, n0;
    supertile_remap(m0, n0);
    float4_ acc[4][4] = {};
    gemm128_main(A, Bt, 1024, m0, n0, As, Bs, acc, false);

    int lane = threadIdx.x & 63, wave = threadIdx.x >> 6;
    int wm = (wave >> 1) * 64, wn = (wave & 1) * 64;
    int lr = lane & 15, lg = lane >> 4;
    #pragma unroll
    for (int i = 0; i < 4; i++)
        #pragma unroll
        for (int j = 0; j < 4; j++) {
            int n = n0 + wn + 16 * j + lr;
            float bv = bias[n];
            #pragma unroll
            for (int r = 0; r < 4; r++) {
                int m = m0 + wm + 16 * i + lg * 4 + r;
                Out[(size_t)m * 1024 + n] = acc[i][j][r] + bv;
            }
        }
}

// ---------------------------------------------------------------------------
// Flash attention (causal + key pad mask), swapped-QK^T (S^T) softmax,
// double-buffered async K/V staging, defer-max, packed P conversion.
// K staged [key][d], V staged [d][key] (global V pre-transposed).
// Row stride DPAD=72 elems (144B). P-tile rotation swizzle (round 7).
// ---------------------------------------------------------------------------
#define DPAD 72   // padded row stride (elems) = 144B

__global__ __launch_bounds__(256) void attn_fwd(
    const unsigned short* __restrict__ Q,   // [B][H][T][HD], pre-scaled 0.125*log2e
    const unsigned short* __restrict__ Kg,  // [B][H][T][HD]
    const unsigned short* __restrict__ Vg,  // [B][H][HD][T]  (transposed)
    const int* __restrict__ pad,            // [B][T]
    unsigned short* __restrict__ Y)         // [B][T][C]
{
    // [buf][K=0/V=1][64][DPAD] : 2 x 2 x 64 x 72 shorts = 36864 B
    __shared__ unsigned short smem[4 * 64 * DPAD];

    int flat = blockIdx.x;          // 0..2047
    int qb = 31 - (flat >> 6);      // heavy-first (LPT)
    int bh = flat & 63;
    int b  = bh >> 4, h = bh & 15;
    const size_t base = (size_t)bh * Tt * HDd;
    int tid  = threadIdx.x;
    int wave = tid >> 6, lane = tid & 63;
    int lr = lane & 15, lg = lane >> 4;
    int q0 = qb * 64 + wave * 16;
    const int* padRow = pad + b * Tt;

    int r8 = tid >> 3;              // staging row 0..31 (and +32)
    int c8 = (tid & 7) * 8;         // staging col {0,8,...,56}

    short8 qf0 = *(const short8*)&Q[base + (size_t)(q0 + lr) * HDd + lg * 8];
    short8 qf1 = *(const short8*)&Q[base + (size_t)(q0 + lr) * HDd + 32 + lg * 8];

    // per-lane scalars: this lane's q-row is q0 + lr (replicated over lg)
    float m_i = -1e30f, l_i = 0.f;
    float4_ o_acc[4];
    #pragma unroll
    for (int dt = 0; dt < 4; dt++) o_acc[dt] = (float4_){0.f, 0.f, 0.f, 0.f};

    // P rotation-swizzle constants
    int ebase = (lg & 1) * 4;        // k&7 base of this lane's 4 keys
    int hnib  = lg >> 1;             // kb low bit source
    int q2    = (2 * lr) & 7;        // 2q mod 8

    // ---- prologue: prefetch tile 0 into registers ----
    short8 kr0 = *(const short8*)&Kg[base + (size_t)r8 * HDd + c8];
    short8 kr1 = *(const short8*)&Kg[base + (size_t)(r8 + 32) * HDd + c8];
    short8 vr0 = *(const short8*)&Vg[base + (size_t)r8 * Tt + c8];
    short8 vr1 = *(const short8*)&Vg[base + (size_t)(r8 + 32) * Tt + c8];
    int pvld = padRow[lane];

    for (int kt = 0; kt <= qb; kt++) {
        int cur = kt & 1;
        unsigned short* Kt = smem + cur * (2 * 64 * DPAD);   // [key][d]
        unsigned short* Vt = Kt + 64 * DPAD;                 // [d][key]
        // ---- write prefetched regs -> LDS (conflict-free full-row map) ----
        *(short8*)&Kt[r8 * DPAD + c8]        = kr0;
        *(short8*)&Kt[(r8 + 32) * DPAD + c8] = kr1;
        *(short8*)&Vt[r8 * DPAD + c8]        = vr0;
        *(short8*)&Vt[(r8 + 32) * DPAD + c8] = vr1;
        unsigned long long pm = __ballot(pvld != 0);
        __syncthreads();                                     // barrier A

        // ---- issue next tile's loads; land during QK + softmax ----
        if (kt < qb) {
            int k1 = kt * 64 + 64;
            kr0 = *(const short8*)&Kg[base + (size_t)(k1 + r8) * HDd + c8];
            kr1 = *(const short8*)&Kg[base + (size_t)(k1 + r8 + 32) * HDd + c8];
            vr0 = *(const short8*)&Vg[base + (size_t)r8 * Tt + k1 + c8];
            vr1 = *(const short8*)&Vg[base + (size_t)(r8 + 32) * Tt + k1 + c8];
            pvld = padRow[k1 + lane];
        }

        // ---- S^T = (K Q^T): rows = keys, cols = q  (swapped operands) ----
        float4_ s[4];
        #pragma unroll
        for (int nt = 0; nt < 4; nt++) {
            short8 kf0 = *(const short8*)&Kt[(nt * 16 + lr) * DPAD + lg * 8];
            short8 kf1 = *(const short8*)&Kt[(nt * 16 + lr) * DPAD + 32 + lg * 8];
            float4_ a = (float4_){0.f, 0.f, 0.f, 0.f};
            a = bmfma(kf0, qf0, a);
            a = bmfma(kf1, qf1, a);
            s[nt] = a;   // s[nt][r]: key = nt*16 + lg*4 + r, q = lr
        }
        // ---- masking (S^T indices) ----
        if (kt == qb) {
            #pragma unroll
            for (int nt = 0; nt < 4; nt++)
                #pragma unroll
                for (int r = 0; r < 4; r++) {
                    int kl = nt * 16 + lg * 4 + r;       // key local
                    bool kpv = (pm >> kl) & 1ull;
                    // causal: key k0+kl vs qrow q0+lr  ->  kl vs wave*16+lr
                    if (!kpv || kl > wave * 16 + lr) s[nt][r] = -1e30f;
                }
        } else if (pm != ~0ull) {
            #pragma unroll
            for (int nt = 0; nt < 4; nt++)
                #pragma unroll
                for (int r = 0; r < 4; r++) {
                    int kl = nt * 16 + lg * 4 + r;
                    bool kpv = (pm >> kl) & 1ull;
                    s[nt][r] = kpv ? s[nt][r] : -1e30f;
                }
        }
        // ---- online softmax (base 2), per-lane scalar state, defer-max ----
        float v = fmaxf(fmaxf(s[0][0], s[0][1]), fmaxf(s[0][2], s[0][3]));
        #pragma unroll
        for (int nt = 1; nt < 4; nt++)
            v = fmaxf(v, fmaxf(fmaxf(s[nt][0], s[nt][1]), fmaxf(s[nt][2], s[nt][3])));
        v = fmaxf(v, __shfl_xor(v, 16, 64));
        v = fmaxf(v, __shfl_xor(v, 32, 64));
        // T13: only rescale when some row's max grew past THR=8 (base-2).
        bool need = __any(v > m_i + 8.0f);   // wave-uniform
        float alpha = 1.0f;
        if (need) {
            float m_new = fmaxf(m_i, v);
            alpha = ex2(m_i - m_new);
            m_i = m_new;
        }
        float rsum = 0.f;
        #pragma unroll
        for (int nt = 0; nt < 4; nt++)
            #pragma unroll
            for (int r = 0; r < 4; r++) {
                float p = ex2(s[nt][r] - m_i);   // bounded by 2^8 when deferred
                s[nt][r] = p;
                rsum += p;
            }
        rsum += __shfl_xor(rsum, 16, 64);
        rsum += __shfl_xor(rsum, 32, 64);
        l_i = l_i * alpha + rsum;

        // ---- rescale o_acc only when max moved (wave-uniform branch) ----
        if (need) {
            #pragma unroll
            for (int r = 0; r < 4; r++) {
                float ar = __shfl(alpha, (lg << 2) + r, 64);
                #pragma unroll
                for (int dt = 0; dt < 4; dt++)
                    o_acc[dt][r] *= ar;
            }
        }

        __syncthreads();   // barrier B: all waves done reading Kt -> P alias ok

        // ---- P: 4x packed b64 writes via v_cvt_pk_bf16_f32 (T12) ----
        unsigned short* Pw = &Kt[wave * 16 * DPAD];   // per-wave slice (Kt alias)
        #pragma unroll
        for (int nt = 0; nt < 4; nt++) {
            uint2_ w;
            w[0] = cvtpk_bf16(s[nt][0], s[nt][1]);
            w[1] = cvtpk_bf16(s[nt][2], s[nt][3]);
            int p = (2 * nt + hnib - q2) & 7;
            *(uint2_*)&Pw[lr * DPAD + p * 8 + ebase] = w;
        }
        // ---- O += P @ V  (pf reads: p=(kb-2q)&7, kb=lg / 4+lg) ----
        short8 pf0 = *(const short8*)&Pw[lr * DPAD + (((lg - q2) & 7) << 3)];
        short8 pf1 = *(const short8*)&Pw[lr * DPAD + (((4 + lg - q2) & 7) << 3)];
        #pragma unroll
        for (int dt = 0; dt < 4; dt++) {
            int d = dt * 16 + lr;
            short8 vf0 = *(const short8*)&Vt[d * DPAD + lg * 8];
            short8 vf1 = *(const short8*)&Vt[d * DPAD + 32 + lg * 8];
            o_acc[dt] = bmfma(pf0, vf0, o_acc[dt]);
            o_acc[dt] = bmfma(pf1, vf1, o_acc[dt]);
        }
        // no end-of-tile barrier: next tile stages into the other buffer;
        // cross-wave reuse of THIS buffer is fenced by the next barrier A+B.
    }

    // ---- epilogue: Y[b][t][h*64+d] = O / l  (l broadcast to q=lg*4+r) ----
    #pragma unroll
    for (int r = 0; r < 4; r++) {
        float lr_ = __shfl(l_i, (lg << 2) + r, 64);
        int qrow = q0 + lg * 4 + r;
        #pragma unroll
        for (int dt = 0; dt < 4; dt++)
            Y[((size_t)b * Tt + qrow) * Cc + h * HDd + dt * 16 + lr] =
                f2bf(o_acc[dt][r] / lr_);
    }
}

// ---------------------------------------------------------------------------
extern "C" void kernel_launch(void* const* d_in, const int* in_sizes, int n_in,
                              void* d_out, int out_size, void* d_ws, size_t ws_size,
                              hipStream_t stream)
{
    const float* x      = (const float*)d_in[0];
    const int*   pad    = (const int*)d_in[1];
    const float* w_attn = (const float*)d_in[2];
    const float* w_proj = (const float*)d_in[3];
    const float* b_proj = (const float*)d_in[4];
    float*       out    = (float*)d_out;

    // workspace carve-up (bf16 elems). Yb aliases Xb (x-bf16 dead after qkv).
    unsigned short* Wta = (unsigned short*)d_ws;            // 3072*1024
    unsigned short* Wtp = Wta + (size_t)3072 * 1024;        // 1024*1024
    unsigned short* Xb  = Wtp + (size_t)1024 * 1024;        // 8192*1024
    unsigned short* Yb  = Xb;                               // alias
    unsigned short* Qb  = Xb + (size_t)8192 * 1024;
    unsigned short* Kb  = Qb + (size_t)Bb * Hh * Tt * HDd;
    unsigned short* Vb  = Kb + (size_t)Bb * Hh * Tt * HDd;  // [B][H][HD][T]

    // 0) x f32 -> bf16
    convert_f32_bf16<<<dim3(4096), 256, 0, stream>>>(x, Xb);
    // 1) transpose+convert weights to bf16 [N][K]
    transpose_f32_bf16<<<dim3(3072 / 32, 1024 / 32), 256, 0, stream>>>(w_attn, Wta, 1024, 3072);
    transpose_f32_bf16<<<dim3(1024 / 32, 1024 / 32), 256, 0, stream>>>(w_proj, Wtp, 1024, 1024);
    // 2) qkv = x @ w_attn -> head-major Q/K (bf16, Q pre-scaled) + transposed V
    gemm_qkv<<<dim3(8192 / 128, 3072 / 128), 256, 0, stream>>>(Xb, Wta, Qb, Kb, Vb);
    // 3) flash attention (flat grid, heavy-first)
    attn_fwd<<<dim3(2048), 256, 0, stream>>>(Qb, Kb, Vb, pad, Yb);
    // 4) out = y @ w_proj + b_proj (f32 out)
    gemm_proj<<<dim3(8192 / 128, 1024 / 128), 256, 0, stream>>>(Yb, Wtp, b_proj, out);
}